// Round 13
// baseline (151.741 us; speedup 1.0000x reference)
//
#include <hip/hip_runtime.h>
#include <hip/hip_fp16.h>

#define NN 50000
#define NE 800000
#define DD 64
#define NG 64

#define NBKT 196        // ceil(NN/256) coarse buckets (dst >> 8)
#define MAXB 5120       // padded tmp slots per bucket (mean 4082)
#define SRTB 7168       // srt slots per bucket (>= MAXB + 256*7 pad worst case)
#define P1CH 2048       // edges per pass-1 block
#define P1NB ((NE + P1CH - 1) / P1CH)   // 391

// ---------------- pass 1: bin edges by dst>>8 into padded tmp buckets ----------------
__global__ __launch_bounds__(256) void bin_k(const int* __restrict__ ei,
                                             const float* __restrict__ ew,
                                             int* __restrict__ bucket_cnt,
                                             unsigned int* __restrict__ tmp_pay,
                                             unsigned char* __restrict__ tmp_c8) {
    __shared__ int hist[NBKT];
    __shared__ int basec[NBKT];
    const int t = threadIdx.x;
    const int e0 = blockIdx.x * P1CH;
    for (int i = t; i < NBKT; i += 256) hist[i] = 0;
    __syncthreads();
    int rr[8]; int cc[8]; float wwf[8];
    #pragma unroll
    for (int i = 0; i < 8; ++i) {
        int e = e0 + i * 256 + t;
        if (e < NE) {
            rr[i] = ei[e]; cc[i] = ei[NE + e]; wwf[i] = ew[e];
            atomicAdd(&hist[cc[i] >> 8], 1);
        } else cc[i] = -1;
    }
    __syncthreads();
    for (int i = t; i < NBKT; i += 256)
        basec[i] = (hist[i] > 0) ? (i * MAXB + atomicAdd(&bucket_cnt[i], hist[i])) : 0;
    __syncthreads();
    #pragma unroll
    for (int i = 0; i < 8; ++i) {
        if (cc[i] >= 0) {
            int b = cc[i] >> 8;
            int slot = atomicAdd(&basec[b], 1);   // LDS cursor within reservation
            unsigned int hb = (unsigned int)__half_as_ushort(__float2half(wwf[i]));
            tmp_pay[slot] = (hb << 16) | (unsigned int)rr[i];
            tmp_c8[slot] = (unsigned char)(cc[i] & 255);
        }
    }
}

// ---------------- pass 2: per-bucket exact sort + per-node (start,pcnt) + dis ----------
__global__ __launch_bounds__(256) void build_k(const int* __restrict__ bucket_cnt,
                                               const unsigned int* __restrict__ tmp_pay,
                                               const unsigned char* __restrict__ tmp_c8,
                                               unsigned int* __restrict__ srt,
                                               int2* __restrict__ rowse,
                                               float* __restrict__ dis) {
    __shared__ int hist[256];
    __shared__ int cursor[256];
    __shared__ float degf[256];
    __shared__ int wtot[4];
    const int b = blockIdx.x;
    const int t = threadIdx.x;
    const int cntb = bucket_cnt[b];
    const int tbase = b * MAXB;
    hist[t] = 0; degf[t] = 0.0f;
    __syncthreads();
    for (int i = t; i < cntb; i += 256) atomicAdd(&hist[tmp_c8[tbase + i]], 1);
    __syncthreads();
    const int v = hist[t];
    const int pv = (v + 7) & ~7;
    int pre = pv;
    #pragma unroll
    for (int off = 1; off < 64; off <<= 1) {
        int u = __shfl_up(pre, off);
        if ((t & 63) >= off) pre += u;
    }
    if ((t & 63) == 63) wtot[t >> 6] = pre;
    __syncthreads();
    int woff = 0;
    for (int i = 0; i < (t >> 6); ++i) woff += wtot[i];
    const int start = b * SRTB + woff + pre - pv;
    cursor[t] = start;
    __syncthreads();
    for (int i = t; i < cntb; i += 256) {
        unsigned int u = tmp_pay[tbase + i];
        int c8 = tmp_c8[tbase + i];
        int slot = atomicAdd(&cursor[c8], 1);   // LDS
        srt[slot] = u;
        float w = __half2float(__ushort_as_half((unsigned short)(u >> 16)));
        atomicAdd(&degf[c8], w);                // LDS fp32
    }
    __syncthreads();
    for (int i = start + v; i < start + pv; ++i) srt[i] = 0u;
    const int node = b * 256 + t;
    if (node < NN) {
        rowse[node] = make_int2(start, pv);
        dis[node] = rsqrtf(1.0f + degf[t]);
    }
}

// ---------------- GEMM: A' = (act(X) @ W) * dis[row], fp16 out ----------------
template<bool ACT>
__global__ __launch_bounds__(256, 4) void gemm_k(
    const float* __restrict__ X, const float* __restrict__ W,
    const float* __restrict__ bias_prev, const float* __restrict__ dis,
    __half* __restrict__ Ah)
{
    __shared__ float Ws[64][64];   // [k][j]
    __shared__ float Xs[64][68];   // [r][k], +4 pad
    const int t = threadIdx.x;
    const int row0 = blockIdx.x * 64;

    #pragma unroll
    for (int s = t; s < 64 * 64; s += 256) ((float*)Ws)[s] = W[s];
    #pragma unroll
    for (int s = t; s < 64 * 64; s += 256) {
        int r = s >> 6, k = s & 63;
        int row = row0 + r;
        if (row >= NN) row = NN - 1;
        float v = X[(size_t)row * DD + k];
        if (ACT) v = fmaxf(v + bias_prev[k], 0.0f);
        Xs[r][k] = v;
    }
    __syncthreads();

    const int tc = t & 15;
    const int tr = t >> 4;
    float4 acc[4];
    #pragma unroll
    for (int i = 0; i < 4; ++i) acc[i] = make_float4(0.f, 0.f, 0.f, 0.f);

    #pragma unroll 2
    for (int kc = 0; kc < 16; ++kc) {
        const int k = kc * 4;
        float4 w0 = *reinterpret_cast<const float4*>(&Ws[k + 0][tc * 4]);
        float4 w1 = *reinterpret_cast<const float4*>(&Ws[k + 1][tc * 4]);
        float4 w2 = *reinterpret_cast<const float4*>(&Ws[k + 2][tc * 4]);
        float4 w3 = *reinterpret_cast<const float4*>(&Ws[k + 3][tc * 4]);
        #pragma unroll
        for (int i = 0; i < 4; ++i) {
            float4 xv = *reinterpret_cast<const float4*>(&Xs[tr * 4 + i][k]);
            acc[i].x += xv.x * w0.x + xv.y * w1.x + xv.z * w2.x + xv.w * w3.x;
            acc[i].y += xv.x * w0.y + xv.y * w1.y + xv.z * w2.y + xv.w * w3.y;
            acc[i].z += xv.x * w0.z + xv.y * w1.z + xv.z * w2.z + xv.w * w3.z;
            acc[i].w += xv.x * w0.w + xv.y * w1.w + xv.z * w2.w + xv.w * w3.w;
        }
    }

    #pragma unroll
    for (int i = 0; i < 4; ++i) {
        int row = row0 + tr * 4 + i;
        if (row >= NN) break;
        float d = dis[row];
        __half2 h0 = __floats2half2_rn(acc[i].x * d, acc[i].y * d);
        __half2 h1 = __floats2half2_rn(acc[i].z * d, acc[i].w * d);
        uint2 st;
        st.x = *reinterpret_cast<unsigned int*>(&h0);
        st.y = *reinterpret_cast<unsigned int*>(&h1);
        *reinterpret_cast<uint2*>(&Ah[(size_t)row * DD + tc * 4]) = st;
    }
}

// ---------------- fused: gather(layer1) + relu/bias + gemm(W2) -> A2' ----------------
// Block = 64 nodes. Phase 1: 4 waves gather 16 nodes each straight into Xs (LDS).
// Phase 2: R12 gemm core from LDS. Eliminates the B round-trip between layers.
__global__ __launch_bounds__(256, 4) void fused_k(
    const int2* __restrict__ rowse, const unsigned int* __restrict__ srt,
    const float* __restrict__ dis, const __half* __restrict__ Ah,
    const float* __restrict__ W, const float* __restrict__ bias_prev,
    __half* __restrict__ Aout)
{
    __shared__ float Ws[64][64];
    __shared__ float Xs[64][68];
    const int t = threadIdx.x;
    const int w = t >> 6, lane = t & 63;
    const int row0 = blockIdx.x * 64;

    #pragma unroll
    for (int s = t; s < 64 * 64; s += 256) ((float*)Ws)[s] = W[s];

    const float bb = bias_prev[lane];

    // phase 1: gather 16 nodes per wave, relu(dis*(self+sum)+b1) into Xs
    for (int i = 0; i < 16; ++i) {
        const int rl = w * 16 + i;
        const int node = row0 + rl;
        float res = 0.0f;
        if (node < NN) {
            const int2 se = rowse[node];
            float acc0 = __half2float(Ah[(size_t)node * DD + lane]);
            float acc1 = 0.0f, acc2 = 0.0f, acc3 = 0.0f;
            const unsigned int* p = srt + se.x;
            uint4 u0 = *reinterpret_cast<const uint4*>(p);
            uint4 u1 = *reinterpret_cast<const uint4*>(p + 4);
            for (int n = se.y; n > 0; n -= 8) {
                uint4 n0, n1;
                if (n > 8) {
                    p += 8;
                    n0 = *reinterpret_cast<const uint4*>(p);
                    n1 = *reinterpret_cast<const uint4*>(p + 4);
                }
                __half h0 = Ah[(size_t)(u0.x & 0xffffu) * DD + lane];
                __half h1 = Ah[(size_t)(u0.y & 0xffffu) * DD + lane];
                __half h2 = Ah[(size_t)(u0.z & 0xffffu) * DD + lane];
                __half h3 = Ah[(size_t)(u0.w & 0xffffu) * DD + lane];
                __half h4 = Ah[(size_t)(u1.x & 0xffffu) * DD + lane];
                __half h5 = Ah[(size_t)(u1.y & 0xffffu) * DD + lane];
                __half h6 = Ah[(size_t)(u1.z & 0xffffu) * DD + lane];
                __half h7 = Ah[(size_t)(u1.w & 0xffffu) * DD + lane];
                acc0 += __half2float(__ushort_as_half((unsigned short)(u0.x >> 16))) * __half2float(h0);
                acc1 += __half2float(__ushort_as_half((unsigned short)(u0.y >> 16))) * __half2float(h1);
                acc2 += __half2float(__ushort_as_half((unsigned short)(u0.z >> 16))) * __half2float(h2);
                acc3 += __half2float(__ushort_as_half((unsigned short)(u0.w >> 16))) * __half2float(h3);
                acc0 += __half2float(__ushort_as_half((unsigned short)(u1.x >> 16))) * __half2float(h4);
                acc1 += __half2float(__ushort_as_half((unsigned short)(u1.y >> 16))) * __half2float(h5);
                acc2 += __half2float(__ushort_as_half((unsigned short)(u1.z >> 16))) * __half2float(h6);
                acc3 += __half2float(__ushort_as_half((unsigned short)(u1.w >> 16))) * __half2float(h7);
                u0 = n0; u1 = n1;
            }
            res = fmaxf(dis[node] * ((acc0 + acc1) + (acc2 + acc3)) + bb, 0.0f);
        }
        Xs[rl][lane] = res;
    }
    __syncthreads();

    // phase 2: gemm from LDS
    const int tc = t & 15;
    const int tr = t >> 4;
    float4 acc[4];
    #pragma unroll
    for (int i = 0; i < 4; ++i) acc[i] = make_float4(0.f, 0.f, 0.f, 0.f);

    #pragma unroll 2
    for (int kc = 0; kc < 16; ++kc) {
        const int k = kc * 4;
        float4 w0 = *reinterpret_cast<const float4*>(&Ws[k + 0][tc * 4]);
        float4 w1 = *reinterpret_cast<const float4*>(&Ws[k + 1][tc * 4]);
        float4 w2 = *reinterpret_cast<const float4*>(&Ws[k + 2][tc * 4]);
        float4 w3 = *reinterpret_cast<const float4*>(&Ws[k + 3][tc * 4]);
        #pragma unroll
        for (int i = 0; i < 4; ++i) {
            float4 xv = *reinterpret_cast<const float4*>(&Xs[tr * 4 + i][k]);
            acc[i].x += xv.x * w0.x + xv.y * w1.x + xv.z * w2.x + xv.w * w3.x;
            acc[i].y += xv.x * w0.y + xv.y * w1.y + xv.z * w2.y + xv.w * w3.y;
            acc[i].z += xv.x * w0.z + xv.y * w1.z + xv.z * w2.z + xv.w * w3.z;
            acc[i].w += xv.x * w0.w + xv.y * w1.w + xv.z * w2.w + xv.w * w3.w;
        }
    }

    #pragma unroll
    for (int i = 0; i < 4; ++i) {
        int row = row0 + tr * 4 + i;
        if (row >= NN) break;
        float d = dis[row];
        __half2 h0 = __floats2half2_rn(acc[i].x * d, acc[i].y * d);
        __half2 h1 = __floats2half2_rn(acc[i].z * d, acc[i].w * d);
        uint2 st;
        st.x = *reinterpret_cast<unsigned int*>(&h0);
        st.y = *reinterpret_cast<unsigned int*>(&h1);
        *reinterpret_cast<uint2*>(&Aout[(size_t)row * DD + tc * 4]) = st;
    }
}

// ---------------- gather (final layer): B[c] = dis[c] * (A'[c] + sum w*A'[r]) --------
__global__ __launch_bounds__(256) void gather_k(
    const int2* __restrict__ rowse, const unsigned int* __restrict__ srt,
    const float* __restrict__ dis,
    const __half* __restrict__ Ah, float* __restrict__ B)
{
    const int node = blockIdx.x * 4 + (threadIdx.x >> 6);
    const int lane = threadIdx.x & 63;
    if (node >= NN) return;
    const int2 se = rowse[node];
    float acc0 = __half2float(Ah[(size_t)node * DD + lane]);  // self-loop term
    float acc1 = 0.0f, acc2 = 0.0f, acc3 = 0.0f;
    const unsigned int* p = srt + se.x;
    uint4 u0 = *reinterpret_cast<const uint4*>(p);
    uint4 u1 = *reinterpret_cast<const uint4*>(p + 4);
    for (int n = se.y; n > 0; n -= 8) {
        uint4 n0, n1;
        if (n > 8) {
            p += 8;
            n0 = *reinterpret_cast<const uint4*>(p);
            n1 = *reinterpret_cast<const uint4*>(p + 4);
        }
        __half h0 = Ah[(size_t)(u0.x & 0xffffu) * DD + lane];
        __half h1 = Ah[(size_t)(u0.y & 0xffffu) * DD + lane];
        __half h2 = Ah[(size_t)(u0.z & 0xffffu) * DD + lane];
        __half h3 = Ah[(size_t)(u0.w & 0xffffu) * DD + lane];
        __half h4 = Ah[(size_t)(u1.x & 0xffffu) * DD + lane];
        __half h5 = Ah[(size_t)(u1.y & 0xffffu) * DD + lane];
        __half h6 = Ah[(size_t)(u1.z & 0xffffu) * DD + lane];
        __half h7 = Ah[(size_t)(u1.w & 0xffffu) * DD + lane];
        acc0 += __half2float(__ushort_as_half((unsigned short)(u0.x >> 16))) * __half2float(h0);
        acc1 += __half2float(__ushort_as_half((unsigned short)(u0.y >> 16))) * __half2float(h1);
        acc2 += __half2float(__ushort_as_half((unsigned short)(u0.z >> 16))) * __half2float(h2);
        acc3 += __half2float(__ushort_as_half((unsigned short)(u0.w >> 16))) * __half2float(h3);
        acc0 += __half2float(__ushort_as_half((unsigned short)(u1.x >> 16))) * __half2float(h4);
        acc1 += __half2float(__ushort_as_half((unsigned short)(u1.y >> 16))) * __half2float(h5);
        acc2 += __half2float(__ushort_as_half((unsigned short)(u1.z >> 16))) * __half2float(h6);
        acc3 += __half2float(__ushort_as_half((unsigned short)(u1.w >> 16))) * __half2float(h7);
        u0 = n0; u1 = n1;
    }
    B[(size_t)node * DD + lane] = dis[node] * ((acc0 + acc1) + (acc2 + acc3));
}

// ---------------- pooling: 32 rows per block ----------------
__global__ __launch_bounds__(64) void pool(
    const float* __restrict__ B, const float* __restrict__ b2,
    const int* __restrict__ batch,
    float* __restrict__ sums, float* __restrict__ cnts, int n)
{
    const int lane = threadIdx.x;
    const int start = blockIdx.x * 32;
    const int end = min(start + 32, n);
    const float bb = b2[lane];
    float acc = 0.0f;
    int cn = 0;
    int curg = batch[start];
    for (int i = start; i < end; ++i) {
        int g = batch[i];
        if (g != curg) {
            unsafeAtomicAdd(&sums[curg * DD + lane], acc);
            if (lane == 0) unsafeAtomicAdd(&cnts[curg], (float)cn);
            acc = 0.0f; cn = 0; curg = g;
        }
        acc += fmaxf(B[(size_t)i * DD + lane] + bb, 0.0f);
        cn++;
    }
    if (cn > 0) {
        unsafeAtomicAdd(&sums[curg * DD + lane], acc);
        if (lane == 0) unsafeAtomicAdd(&cnts[curg], (float)cn);
    }
}

__global__ void finalize(const float* __restrict__ sums, const float* __restrict__ cnts,
                         float* __restrict__ out) {
    int i = blockIdx.x * blockDim.x + threadIdx.x;
    if (i < NG * DD) {
        int g = i >> 6;
        out[i] = sums[i] / fmaxf(cnts[g], 1.0f);
    }
}

// ---------------- host ----------------
extern "C" void kernel_launch(void* const* d_in, const int* in_sizes, int n_in,
                              void* d_out, int out_size, void* d_ws, size_t ws_size,
                              hipStream_t stream) {
    const float* x   = (const float*)d_in[0];
    const int*   ei  = (const int*)  d_in[1];
    const float* ew  = (const float*)d_in[2];
    const int*   bat = (const int*)  d_in[3];
    const float* W1  = (const float*)d_in[4];
    const float* b1  = (const float*)d_in[5];
    const float* W2  = (const float*)d_in[6];
    const float* b2  = (const float*)d_in[7];
    float* out = (float*)d_out;

    char* ws = (char*)d_ws;
    size_t off = 0;
    __half* Ah        = (__half*)(ws + off); off += (size_t)NN * DD * 2;          // 6.4 MB
    __half* Ah2       = (__half*)(ws + off); off += (size_t)NN * DD * 2;          // 6.4 MB
    float*  B         = (float*) (ws + off); off += (size_t)NN * DD * 4;          // 12.8 MB
    unsigned int* srt = (unsigned int*)(ws + off); off += (size_t)NBKT * SRTB * 4; // 5.6 MB
    unsigned int* tmp_pay = (unsigned int*)(ws + off); off += (size_t)NBKT * MAXB * 4;  // 4.0 MB
    unsigned char* tmp_c8 = (unsigned char*)(ws + off); off += (size_t)NBKT * MAXB;     // 1.0 MB
    int2*   rowse      = (int2*)(ws + off); off += (size_t)NN * 8;
    float*  dis        = (float*)(ws + off); off += (size_t)NN * 4;
    // contiguous zero-init region: bucket_cnt | sums | cnts
    int*    bucket_cnt = (int*)  (ws + off); off += (size_t)NBKT * 4;
    float*  sums       = (float*)(ws + off); off += (size_t)NG * DD * 4;
    float*  cnts       = (float*)(ws + off); off += (size_t)NG * 4;

    (void)hipMemsetAsync(bucket_cnt, 0, (size_t)(NBKT + NG * DD + NG) * 4, stream);

    // CSR build (shared by both layers) — no per-edge global atomics
    bin_k<<<P1NB, 256, 0, stream>>>(ei, ew, bucket_cnt, tmp_pay, tmp_c8);
    build_k<<<NBKT, 256, 0, stream>>>(bucket_cnt, tmp_pay, tmp_c8, srt, rowse, dis);

    // layer 1 GEMM
    gemm_k<false><<<(NN + 63) / 64, 256, 0, stream>>>(x, W1, nullptr, dis, Ah);
    // layer-1 aggregation + relu/bias + layer-2 GEMM, fused (no B round-trip)
    fused_k<<<(NN + 63) / 64, 256, 0, stream>>>(rowse, srt, dis, Ah, W2, b1, Ah2);
    // layer-2 aggregation
    gather_k<<<(NN + 3) / 4, 256, 0, stream>>>(rowse, srt, dis, Ah2, B);

    // pooling (bias+relu fused on read)
    pool<<<(NN + 31) / 32, 64, 0, stream>>>(B, b2, bat, sums, cnts, NN);
    finalize<<<(NG * DD + 255) / 256, 256, 0, stream>>>(sums, cnts, out);
}

// Round 14
// 139.965 us; speedup vs baseline: 1.0841x; 1.0841x over previous
//
#include <hip/hip_runtime.h>
#include <hip/hip_fp16.h>

#define NN 50000
#define NE 800000
#define DD 64
#define NG 64

#define NBKT 196        // ceil(NN/256) coarse buckets (dst >> 8)
#define MAXB 5120       // padded tmp slots per bucket (mean 4082)
#define SRTB 7168       // srt slots per bucket (>= MAXB + 256*7 pad worst case)
#define P1CH 2048       // edges per pass-1 block
#define P1NB ((NE + P1CH - 1) / P1CH)   // 391

// ---------------- pass 1: bin edges by dst>>8 into padded tmp buckets ----------------
__global__ __launch_bounds__(256) void bin_k(const int* __restrict__ ei,
                                             const float* __restrict__ ew,
                                             int* __restrict__ bucket_cnt,
                                             unsigned int* __restrict__ tmp_pay,
                                             unsigned char* __restrict__ tmp_c8) {
    __shared__ int hist[NBKT];
    __shared__ int basec[NBKT];
    const int t = threadIdx.x;
    const int e0 = blockIdx.x * P1CH;
    for (int i = t; i < NBKT; i += 256) hist[i] = 0;
    __syncthreads();
    int rr[8]; int cc[8]; float wwf[8];
    #pragma unroll
    for (int i = 0; i < 8; ++i) {
        int e = e0 + i * 256 + t;
        if (e < NE) {
            rr[i] = ei[e]; cc[i] = ei[NE + e]; wwf[i] = ew[e];
            atomicAdd(&hist[cc[i] >> 8], 1);
        } else cc[i] = -1;
    }
    __syncthreads();
    for (int i = t; i < NBKT; i += 256)
        basec[i] = (hist[i] > 0) ? (i * MAXB + atomicAdd(&bucket_cnt[i], hist[i])) : 0;
    __syncthreads();
    #pragma unroll
    for (int i = 0; i < 8; ++i) {
        if (cc[i] >= 0) {
            int b = cc[i] >> 8;
            int slot = atomicAdd(&basec[b], 1);   // LDS cursor within reservation
            unsigned int hb = (unsigned int)__half_as_ushort(__float2half(wwf[i]));
            tmp_pay[slot] = (hb << 16) | (unsigned int)rr[i];
            tmp_c8[slot] = (unsigned char)(cc[i] & 255);
        }
    }
}

// ---------------- pass 2: per-bucket exact sort + per-node (start,pcnt) + dis ----------
__global__ __launch_bounds__(256) void build_k(const int* __restrict__ bucket_cnt,
                                               const unsigned int* __restrict__ tmp_pay,
                                               const unsigned char* __restrict__ tmp_c8,
                                               unsigned int* __restrict__ srt,
                                               int2* __restrict__ rowse,
                                               float* __restrict__ dis) {
    __shared__ int hist[256];
    __shared__ int cursor[256];
    __shared__ float degf[256];
    __shared__ int wtot[4];
    const int b = blockIdx.x;
    const int t = threadIdx.x;
    const int cntb = bucket_cnt[b];
    const int tbase = b * MAXB;
    hist[t] = 0; degf[t] = 0.0f;
    __syncthreads();
    for (int i = t; i < cntb; i += 256) atomicAdd(&hist[tmp_c8[tbase + i]], 1);
    __syncthreads();
    const int v = hist[t];
    const int pv = (v + 7) & ~7;
    int pre = pv;
    #pragma unroll
    for (int off = 1; off < 64; off <<= 1) {
        int u = __shfl_up(pre, off);
        if ((t & 63) >= off) pre += u;
    }
    if ((t & 63) == 63) wtot[t >> 6] = pre;
    __syncthreads();
    int woff = 0;
    for (int i = 0; i < (t >> 6); ++i) woff += wtot[i];
    const int start = b * SRTB + woff + pre - pv;
    cursor[t] = start;
    __syncthreads();
    for (int i = t; i < cntb; i += 256) {
        unsigned int u = tmp_pay[tbase + i];
        int c8 = tmp_c8[tbase + i];
        int slot = atomicAdd(&cursor[c8], 1);   // LDS
        srt[slot] = u;
        float w = __half2float(__ushort_as_half((unsigned short)(u >> 16)));
        atomicAdd(&degf[c8], w);                // LDS fp32
    }
    __syncthreads();
    for (int i = start + v; i < start + pv; ++i) srt[i] = 0u;
    const int node = b * 256 + t;
    if (node < NN) {
        rowse[node] = make_int2(start, pv);
        dis[node] = rsqrtf(1.0f + degf[t]);
    }
}

// ---------------- GEMM: A' = (act(X) @ W) * dis[row], fp16 out ----------------
template<bool ACT>
__global__ __launch_bounds__(256, 4) void gemm_k(
    const float* __restrict__ X, const float* __restrict__ W,
    const float* __restrict__ bias_prev, const float* __restrict__ dis,
    __half* __restrict__ Ah)
{
    __shared__ float Ws[64][64];   // [k][j]
    __shared__ float Xs[64][68];   // [r][k], +4 pad
    const int t = threadIdx.x;
    const int row0 = blockIdx.x * 64;

    #pragma unroll
    for (int s = t; s < 64 * 64; s += 256) ((float*)Ws)[s] = W[s];
    #pragma unroll
    for (int s = t; s < 64 * 64; s += 256) {
        int r = s >> 6, k = s & 63;
        int row = row0 + r;
        if (row >= NN) row = NN - 1;
        float v = X[(size_t)row * DD + k];
        if (ACT) v = fmaxf(v + bias_prev[k], 0.0f);
        Xs[r][k] = v;
    }
    __syncthreads();

    const int tc = t & 15;
    const int tr = t >> 4;
    float4 acc[4];
    #pragma unroll
    for (int i = 0; i < 4; ++i) acc[i] = make_float4(0.f, 0.f, 0.f, 0.f);

    #pragma unroll 2
    for (int kc = 0; kc < 16; ++kc) {
        const int k = kc * 4;
        float4 w0 = *reinterpret_cast<const float4*>(&Ws[k + 0][tc * 4]);
        float4 w1 = *reinterpret_cast<const float4*>(&Ws[k + 1][tc * 4]);
        float4 w2 = *reinterpret_cast<const float4*>(&Ws[k + 2][tc * 4]);
        float4 w3 = *reinterpret_cast<const float4*>(&Ws[k + 3][tc * 4]);
        #pragma unroll
        for (int i = 0; i < 4; ++i) {
            float4 xv = *reinterpret_cast<const float4*>(&Xs[tr * 4 + i][k]);
            acc[i].x += xv.x * w0.x + xv.y * w1.x + xv.z * w2.x + xv.w * w3.x;
            acc[i].y += xv.x * w0.y + xv.y * w1.y + xv.z * w2.y + xv.w * w3.y;
            acc[i].z += xv.x * w0.z + xv.y * w1.z + xv.z * w2.z + xv.w * w3.z;
            acc[i].w += xv.x * w0.w + xv.y * w1.w + xv.z * w2.w + xv.w * w3.w;
        }
    }

    #pragma unroll
    for (int i = 0; i < 4; ++i) {
        int row = row0 + tr * 4 + i;
        if (row >= NN) break;
        float d = dis[row];
        __half2 h0 = __floats2half2_rn(acc[i].x * d, acc[i].y * d);
        __half2 h1 = __floats2half2_rn(acc[i].z * d, acc[i].w * d);
        uint2 st;
        st.x = *reinterpret_cast<unsigned int*>(&h0);
        st.y = *reinterpret_cast<unsigned int*>(&h1);
        *reinterpret_cast<uint2*>(&Ah[(size_t)row * DD + tc * 4]) = st;
    }
}

// ---------------- gather: B[c] = dis[c] * (A'[c] + sum_e w_e * A'[r_e]) ----------------
// One wave per node; halves split the edge stream (h0: edges 0-3 of each 8-block,
// h1: edges 4-7). Each lane loads __half2 (2 features) -> one VMEM instruction
// covers TWO rows; 8 rows in flight per wave with half the instructions.
__global__ __launch_bounds__(256) void gather_k(
    const int2* __restrict__ rowse, const unsigned int* __restrict__ srt,
    const float* __restrict__ dis,
    const __half2* __restrict__ Ah2, float* __restrict__ B)
{
    const int node = blockIdx.x * 4 + (threadIdx.x >> 6);
    const int wl = threadIdx.x & 63;
    const int h = wl >> 5;     // which half of each 8-edge block
    const int l = wl & 31;     // feature-pair index
    if (node >= NN) return;
    const int2 se = rowse[node];
    float ax0 = 0.f, ay0 = 0.f, ax1 = 0.f, ay1 = 0.f;
    if (h == 0) {              // self-loop term on half 0
        __half2 s = Ah2[(size_t)node * 32 + l];
        ax0 = __half2float(__low2half(s));
        ay0 = __half2float(__high2half(s));
    }
    const unsigned int* p = srt + se.x + h * 4;
    for (int n = se.y; n > 0; n -= 8, p += 8) {
        uint4 u = *reinterpret_cast<const uint4*>(p);   // this half's 4 edges
        __half2 a0 = Ah2[(size_t)(u.x & 0xffffu) * 32 + l];
        __half2 a1 = Ah2[(size_t)(u.y & 0xffffu) * 32 + l];
        __half2 a2 = Ah2[(size_t)(u.z & 0xffffu) * 32 + l];
        __half2 a3 = Ah2[(size_t)(u.w & 0xffffu) * 32 + l];
        float w0 = __half2float(__ushort_as_half((unsigned short)(u.x >> 16)));
        float w1 = __half2float(__ushort_as_half((unsigned short)(u.y >> 16)));
        float w2 = __half2float(__ushort_as_half((unsigned short)(u.z >> 16)));
        float w3 = __half2float(__ushort_as_half((unsigned short)(u.w >> 16)));
        ax0 += w0 * __half2float(__low2half(a0));
        ay0 += w0 * __half2float(__high2half(a0));
        ax1 += w1 * __half2float(__low2half(a1));
        ay1 += w1 * __half2float(__high2half(a1));
        ax0 += w2 * __half2float(__low2half(a2));
        ay0 += w2 * __half2float(__high2half(a2));
        ax1 += w3 * __half2float(__low2half(a3));
        ay1 += w3 * __half2float(__high2half(a3));
    }
    float ax = ax0 + ax1, ay = ay0 + ay1;
    ax += __shfl_xor(ax, 32);
    ay += __shfl_xor(ay, 32);
    if (h == 0) {
        float d = dis[node];
        *reinterpret_cast<float2*>(&B[(size_t)node * DD + 2 * l]) =
            make_float2(d * ax, d * ay);
    }
}

// ---------------- pooling: 32 rows per block ----------------
__global__ __launch_bounds__(64) void pool(
    const float* __restrict__ B, const float* __restrict__ b2,
    const int* __restrict__ batch,
    float* __restrict__ sums, float* __restrict__ cnts, int n)
{
    const int lane = threadIdx.x;
    const int start = blockIdx.x * 32;
    const int end = min(start + 32, n);
    const float bb = b2[lane];
    float acc = 0.0f;
    int cn = 0;
    int curg = batch[start];
    for (int i = start; i < end; ++i) {
        int g = batch[i];
        if (g != curg) {
            unsafeAtomicAdd(&sums[curg * DD + lane], acc);
            if (lane == 0) unsafeAtomicAdd(&cnts[curg], (float)cn);
            acc = 0.0f; cn = 0; curg = g;
        }
        acc += fmaxf(B[(size_t)i * DD + lane] + bb, 0.0f);
        cn++;
    }
    if (cn > 0) {
        unsafeAtomicAdd(&sums[curg * DD + lane], acc);
        if (lane == 0) unsafeAtomicAdd(&cnts[curg], (float)cn);
    }
}

__global__ void finalize(const float* __restrict__ sums, const float* __restrict__ cnts,
                         float* __restrict__ out) {
    int i = blockIdx.x * blockDim.x + threadIdx.x;
    if (i < NG * DD) {
        int g = i >> 6;
        out[i] = sums[i] / fmaxf(cnts[g], 1.0f);
    }
}

// ---------------- host ----------------
extern "C" void kernel_launch(void* const* d_in, const int* in_sizes, int n_in,
                              void* d_out, int out_size, void* d_ws, size_t ws_size,
                              hipStream_t stream) {
    const float* x   = (const float*)d_in[0];
    const int*   ei  = (const int*)  d_in[1];
    const float* ew  = (const float*)d_in[2];
    const int*   bat = (const int*)  d_in[3];
    const float* W1  = (const float*)d_in[4];
    const float* b1  = (const float*)d_in[5];
    const float* W2  = (const float*)d_in[6];
    const float* b2  = (const float*)d_in[7];
    float* out = (float*)d_out;

    char* ws = (char*)d_ws;
    size_t off = 0;
    __half* Ah        = (__half*)(ws + off); off += (size_t)NN * DD * 2;          // 6.4 MB
    float*  B         = (float*) (ws + off); off += (size_t)NN * DD * 4;          // 12.8 MB
    unsigned int* srt = (unsigned int*)(ws + off); off += (size_t)NBKT * SRTB * 4; // 5.6 MB
    unsigned int* tmp_pay = (unsigned int*)(ws + off); off += (size_t)NBKT * MAXB * 4;  // 4.0 MB
    unsigned char* tmp_c8 = (unsigned char*)(ws + off); off += (size_t)NBKT * MAXB;     // 1.0 MB
    int2*   rowse      = (int2*)(ws + off); off += (size_t)NN * 8;
    float*  dis        = (float*)(ws + off); off += (size_t)NN * 4;
    // contiguous zero-init region: bucket_cnt | sums | cnts
    int*    bucket_cnt = (int*)  (ws + off); off += (size_t)NBKT * 4;
    float*  sums       = (float*)(ws + off); off += (size_t)NG * DD * 4;
    float*  cnts       = (float*)(ws + off); off += (size_t)NG * 4;

    (void)hipMemsetAsync(bucket_cnt, 0, (size_t)(NBKT + NG * DD + NG) * 4, stream);

    // CSR build (shared by both layers) — no per-edge global atomics
    bin_k<<<P1NB, 256, 0, stream>>>(ei, ew, bucket_cnt, tmp_pay, tmp_c8);
    build_k<<<NBKT, 256, 0, stream>>>(bucket_cnt, tmp_pay, tmp_c8, srt, rowse, dis);

    // layer 1
    gemm_k<false><<<(NN + 63) / 64, 256, 0, stream>>>(x, W1, nullptr, dis, Ah);
    gather_k<<<(NN + 3) / 4, 256, 0, stream>>>(rowse, srt, dis, (const __half2*)Ah, B);

    // layer 2
    gemm_k<true><<<(NN + 63) / 64, 256, 0, stream>>>(B, W2, b1, dis, Ah);
    gather_k<<<(NN + 3) / 4, 256, 0, stream>>>(rowse, srt, dis, (const __half2*)Ah, B);

    // pooling (bias+relu fused on read)
    pool<<<(NN + 31) / 32, 64, 0, stream>>>(B, b2, bat, sums, cnts, NN);
    finalize<<<(NG * DD + 255) / 256, 256, 0, stream>>>(sums, cnts, out);
}